// Round 1
// baseline (933.817 us; speedup 1.0000x reference)
//
#include <hip/hip_runtime.h>
#include <math.h>

#define NB   4
#define NSEQ 8192
#define CDIM 64
#define M    2048      // window length
#define NW   7         // windows per batch
#define PAD  68        // LDS row pitch (floats): 2-way-max bank aliasing, keeps 16B align

// window w: gathered global position = base + stride * j   (j = window-local index)
__device__ __forceinline__ int win_base(int w) {
    return (w < 4) ? (w << 11) : ((w < 6) ? ((w - 4) << 12) : 0);
}
__device__ __forceinline__ int win_stride(int w) {
    return (w < 4) ? 1 : ((w < 6) ? 2 : 4);
}

// ---------------- kernel 1: QKV projection  Q/K/V = x @ W{q,k,v} ----------------
__global__ __launch_bounds__(256) void qkv_proj(
        const float* __restrict__ x,
        const float* __restrict__ Wq, const float* __restrict__ Wk,
        const float* __restrict__ Wv,
        float* __restrict__ Q, float* __restrict__ K, float* __restrict__ V) {
    __shared__ __align__(16) float sW[3][64][64];
    __shared__ __align__(16) float xs[4][64];
    const int tid = threadIdx.x;
    for (int i = tid; i < 4096; i += 256) {
        sW[0][i >> 6][i & 63] = Wq[i];
        sW[1][i >> 6][i & 63] = Wk[i];
        sW[2][i >> 6][i & 63] = Wv[i];
    }
    __syncthreads();
    const int col = tid & 63, rg = tid >> 6;
    const long rowbase = (long)blockIdx.x * 128;
    for (int r0 = 0; r0 < 128; r0 += 4) {
        const long row = rowbase + r0 + rg;
        xs[rg][col] = x[row * 64 + col];
        __syncthreads();
        float aq = 0.f, ak = 0.f, av = 0.f;
#pragma unroll
        for (int i = 0; i < 64; i += 4) {
            const float4 xv = *(const float4*)&xs[rg][i];
            aq += xv.x * sW[0][i][col] + xv.y * sW[0][i + 1][col]
                + xv.z * sW[0][i + 2][col] + xv.w * sW[0][i + 3][col];
            ak += xv.x * sW[1][i][col] + xv.y * sW[1][i + 1][col]
                + xv.z * sW[1][i + 2][col] + xv.w * sW[1][i + 3][col];
            av += xv.x * sW[2][i][col] + xv.y * sW[2][i + 1][col]
                + xv.z * sW[2][i + 2][col] + xv.w * sW[2][i + 3][col];
        }
        Q[row * 64 + col] = aq;
        K[row * 64 + col] = ak;
        V[row * 64 + col] = av;
        __syncthreads();
    }
}

// ---------------- kernel 2: causal flash attention per (b, window, q-tile) -------
// block = 256 threads, q-tile = 64 rows, k-tile = 64 rows.
// thread (qg=tid>>4, kg=tid&15) owns S[q=qg*4+j][k=kg+16*i] and O[q=qg*4+j][d=kg*4..+3]
__global__ __launch_bounds__(256) void attn(
        const float* __restrict__ Q, const float* __restrict__ K,
        const float* __restrict__ V,
        float* __restrict__ O, float* __restrict__ LSE) {
    __shared__ __align__(16) float Qs[64][PAD];
    __shared__ __align__(16) float KPs[64][PAD];   // K tile, then aliased as P tile
    __shared__ __align__(16) float Vs[64][PAD];

    const int tid = threadIdx.x;
    const int qt  = 31 - (int)blockIdx.x;   // heavy tiles launch first
    const int w   = blockIdx.y;
    const int b   = blockIdx.z;
    const int base = win_base(w), stride = win_stride(w);

    const float* Qb = Q + (long)b * NSEQ * CDIM;
    const float* Kb = K + (long)b * NSEQ * CDIM;
    const float* Vb = V + (long)b * NSEQ * CDIM;

    // load Q tile (gathered rows)
    {
        const int r = tid >> 2;
        const int g = base + stride * (qt * 64 + r);
        const float4* src = (const float4*)(Qb + (long)g * CDIM);
#pragma unroll
        for (int it = 0; it < 4; ++it) {
            const int c4 = (tid & 3) + 4 * it;
            *(float4*)&Qs[r][c4 * 4] = src[c4];
        }
    }

    const int qg = tid >> 4, kg = tid & 15;
    float m_[4], l_[4], o_[4][4];
#pragma unroll
    for (int j = 0; j < 4; ++j) {
        m_[j] = -1e30f; l_[j] = 0.f;
#pragma unroll
        for (int d = 0; d < 4; ++d) o_[j][d] = 0.f;
    }

    for (int kt = 0; kt <= qt; ++kt) {
        __syncthreads();   // prev PV reads of KPs/Vs done (and Q-tile visible on iter 0)
        // stage K/V tile
        {
            const int r = tid >> 2;
            const int g = base + stride * (kt * 64 + r);
            const float4* ksrc = (const float4*)(Kb + (long)g * CDIM);
            const float4* vsrc = (const float4*)(Vb + (long)g * CDIM);
#pragma unroll
            for (int it = 0; it < 4; ++it) {
                const int c4 = (tid & 3) + 4 * it;
                *(float4*)&KPs[r][c4 * 4] = ksrc[c4];
                *(float4*)&Vs[r][c4 * 4]  = vsrc[c4];
            }
        }
        __syncthreads();

        // S = Q K^T (4q x 4k per thread)
        float s[4][4];
#pragma unroll
        for (int j = 0; j < 4; ++j)
#pragma unroll
            for (int i = 0; i < 4; ++i) s[j][i] = 0.f;
#pragma unroll
        for (int c = 0; c < 64; c += 4) {
            float4 qv[4], kv[4];
#pragma unroll
            for (int j = 0; j < 4; ++j) qv[j] = *(const float4*)&Qs[qg * 4 + j][c];
#pragma unroll
            for (int i = 0; i < 4; ++i) kv[i] = *(const float4*)&KPs[kg + 16 * i][c];
#pragma unroll
            for (int j = 0; j < 4; ++j)
#pragma unroll
                for (int i = 0; i < 4; ++i)
                    s[j][i] += qv[j].x * kv[i].x + qv[j].y * kv[i].y
                             + qv[j].z * kv[i].z + qv[j].w * kv[i].w;
        }
#pragma unroll
        for (int j = 0; j < 4; ++j)
#pragma unroll
            for (int i = 0; i < 4; ++i) s[j][i] *= 0.125f;   // 1/sqrt(64)
        if (kt == qt) {   // causal mask inside diagonal tile (window-local indices)
#pragma unroll
            for (int j = 0; j < 4; ++j)
#pragma unroll
                for (int i = 0; i < 4; ++i)
                    if (kg + 16 * i > qg * 4 + j) s[j][i] = -1e30f;
        }
        __syncthreads();   // all K reads done before P overwrites KPs

        // online softmax + write P
#pragma unroll
        for (int j = 0; j < 4; ++j) {
            float tm = fmaxf(fmaxf(s[j][0], s[j][1]), fmaxf(s[j][2], s[j][3]));
#pragma unroll
            for (int d = 1; d < 16; d <<= 1) tm = fmaxf(tm, __shfl_xor(tm, d, 16));
            const float mn = fmaxf(m_[j], tm);
            const float sc = __expf(m_[j] - mn);
            float p[4], rs = 0.f;
#pragma unroll
            for (int i = 0; i < 4; ++i) { p[i] = __expf(s[j][i] - mn); rs += p[i]; }
#pragma unroll
            for (int d = 1; d < 16; d <<= 1) rs += __shfl_xor(rs, d, 16);
            l_[j] = l_[j] * sc + rs;
            m_[j] = mn;
#pragma unroll
            for (int d = 0; d < 4; ++d) o_[j][d] *= sc;
#pragma unroll
            for (int i = 0; i < 4; ++i) KPs[qg * 4 + j][kg + 16 * i] = p[i];
        }
        __syncthreads();   // P visible to all

        // O += P V  (4q x 4d per thread)
#pragma unroll
        for (int kk = 0; kk < 64; kk += 4) {
            float4 pv[4], vv[4];
#pragma unroll
            for (int j = 0; j < 4; ++j) pv[j] = *(const float4*)&KPs[qg * 4 + j][kk];
#pragma unroll
            for (int i = 0; i < 4; ++i) vv[i] = *(const float4*)&Vs[kk + i][kg * 4];
#pragma unroll
            for (int j = 0; j < 4; ++j) {
                o_[j][0] += pv[j].x * vv[0].x + pv[j].y * vv[1].x + pv[j].z * vv[2].x + pv[j].w * vv[3].x;
                o_[j][1] += pv[j].x * vv[0].y + pv[j].y * vv[1].y + pv[j].z * vv[2].y + pv[j].w * vv[3].y;
                o_[j][2] += pv[j].x * vv[0].z + pv[j].y * vv[1].z + pv[j].z * vv[2].z + pv[j].w * vv[3].z;
                o_[j][3] += pv[j].x * vv[0].w + pv[j].y * vv[1].w + pv[j].z * vv[2].w + pv[j].w * vv[3].w;
            }
        }
    }

    // epilogue: normalize, store O and lse
#pragma unroll
    for (int j = 0; j < 4; ++j) {
        const float inv = 1.0f / l_[j];
        const int row = qt * 64 + qg * 4 + j;
        const long off = ((long)(b * NW + w) * M + row) * CDIM + kg * 4;
        float4 ov;
        ov.x = o_[j][0] * inv; ov.y = o_[j][1] * inv;
        ov.z = o_[j][2] * inv; ov.w = o_[j][3] * inv;
        *(float4*)&O[off] = ov;
        if (kg == 0) LSE[(long)(b * NW + w) * M + row] = m_[j] + __logf(l_[j]);
    }
}

// ---------------- kernel 3: mix windows into out (closed-form inverse gather) ----
__global__ __launch_bounds__(256) void mix_out(
        const float* __restrict__ O, const float* __restrict__ LSE,
        float* __restrict__ out) {
    const int gid = blockIdx.x * 256 + threadIdx.x;    // [0, 4*8192*16)
    const int f4 = gid & 15;
    const int t  = (gid >> 4) & (NSEQ - 1);
    const int b  = gid >> 17;

    const int w1 = t >> 11, j1 = t & (M - 1);
    const long i1 = (long)(b * NW + w1) * M + j1;
    const float lse1 = LSE[i1];
    const float4 o1 = *(const float4*)&O[i1 * CDIM + f4 * 4];

    const bool h2 = (t & 1) == 0;
    const bool h3 = (t & 3) == 0;
    float lse2 = -1e30f, lse3 = -1e30f;
    float4 o2 = make_float4(0.f, 0.f, 0.f, 0.f);
    float4 o3 = make_float4(0.f, 0.f, 0.f, 0.f);
    if (h2) {
        const int w2 = 4 + (t >> 12), j2 = (t & 4095) >> 1;
        const long i2 = (long)(b * NW + w2) * M + j2;
        lse2 = LSE[i2];
        o2 = *(const float4*)&O[i2 * CDIM + f4 * 4];
    }
    if (h3) {
        const int j3 = t >> 2;
        const long i3 = (long)(b * NW + 6) * M + j3;
        lse3 = LSE[i3];
        o3 = *(const float4*)&O[i3 * CDIM + f4 * 4];
    }
    const float mm = fmaxf(lse1, fmaxf(lse2, lse3));
    float a1 = __expf(lse1 - mm);
    float a2 = h2 ? __expf(lse2 - mm) : 0.f;
    float a3 = h3 ? __expf(lse3 - mm) : 0.f;
    const float inv = 1.f / (a1 + a2 + a3);
    a1 *= inv; a2 *= inv; a3 *= inv;
    float4 r;
    r.x = o1.x * a1 + o2.x * a2 + o3.x * a3;
    r.y = o1.y * a1 + o2.y * a2 + o3.y * a3;
    r.z = o1.z * a1 + o2.z * a2 + o3.z * a3;
    r.w = o1.w * a1 + o2.w * a2 + o3.w * a3;
    *(float4*)&out[(long)gid * 4] = r;
}

extern "C" void kernel_launch(void* const* d_in, const int* in_sizes, int n_in,
                              void* d_out, int out_size, void* d_ws, size_t ws_size,
                              hipStream_t stream) {
    const float* x  = (const float*)d_in[0];
    const float* Wq = (const float*)d_in[1];
    const float* Wk = (const float*)d_in[2];
    const float* Wv = (const float*)d_in[3];
    float* out = (float*)d_out;
    float* ws  = (float*)d_ws;

    const long QN = (long)NB * NSEQ * CDIM;          // 2,097,152 floats per tensor
    float* Q   = ws;
    float* K   = ws + QN;
    float* V   = ws + 2 * QN;
    float* O   = ws + 3 * QN;                        // [b][w][2048][64]
    float* LSE = O + (long)NB * NW * M * CDIM;       // [b][w][2048]

    qkv_proj<<<256, 256, 0, stream>>>(x, Wq, Wk, Wv, Q, K, V);
    attn<<<dim3(32, NW, NB), 256, 0, stream>>>(Q, K, V, O, LSE);
    mix_out<<<(NB * NSEQ * 16) / 256, 256, 0, stream>>>(O, LSE, out);
}

// Round 2
// 172.957 us; speedup vs baseline: 5.3991x; 5.3991x over previous
//
#include <hip/hip_runtime.h>
#include <math.h>

#define NB   4
#define NSEQ 8192
#define CDIM 64
#define M    2048
#define NW   7
#define NBLK 80      // sub-blocks (qt,ci) per window: 8*1+8*2+8*3+8*4

typedef _Float16 half8 __attribute__((ext_vector_type(8)));
typedef float f32x4 __attribute__((ext_vector_type(4)));
typedef unsigned short u16x8 __attribute__((ext_vector_type(8)));

__device__ __forceinline__ int win_base(int w) {
    return (w < 4) ? (w << 11) : ((w < 6) ? ((w - 4) << 12) : 0);
}
__device__ __forceinline__ int win_stride(int w) {
    return (w < 4) ? 1 : ((w < 6) ? 2 : 4);
}

// ---------------- kernel 1: QKV projection, f16 outputs -------------------
// block = 64 (1 wave): lane owns output column; W columns live in registers
// (192 VGPRs) -> FMA-bound, no per-FMA LDS scalar reads. 32 rows per block.
__global__ __launch_bounds__(64, 1) void qkv_proj(
        const float* __restrict__ x,
        const float* __restrict__ Wq, const float* __restrict__ Wk,
        const float* __restrict__ Wv,
        _Float16* __restrict__ Qg, _Float16* __restrict__ Kg,
        _Float16* __restrict__ Vg) {
    __shared__ __align__(16) float xs[32][64];
    const int lane = threadIdx.x;
    const long rowbase = (long)blockIdx.x * 32;

    float wq[64], wk[64], wv[64];
#pragma unroll
    for (int i = 0; i < 64; ++i) {
        wq[i] = Wq[i * 64 + lane];
        wk[i] = Wk[i * 64 + lane];
        wv[i] = Wv[i * 64 + lane];
    }
#pragma unroll
    for (int i = 0; i < 8; ++i) {
        int idx = lane + i * 64;            // 512 float4 chunks: 32 rows x 16
        int r = idx >> 4, ch = idx & 15;
        *(float4*)&xs[r][ch * 4] = *(const float4*)&x[(rowbase + r) * 64 + ch * 4];
    }
    __syncthreads();
    for (int r = 0; r < 32; ++r) {
        float aq = 0.f, ak = 0.f, av = 0.f;
#pragma unroll
        for (int i = 0; i < 64; i += 4) {
            float4 xv = *(const float4*)&xs[r][i];
            aq += xv.x * wq[i] + xv.y * wq[i + 1] + xv.z * wq[i + 2] + xv.w * wq[i + 3];
            ak += xv.x * wk[i] + xv.y * wk[i + 1] + xv.z * wk[i + 2] + xv.w * wk[i + 3];
            av += xv.x * wv[i] + xv.y * wv[i + 1] + xv.z * wv[i + 2] + xv.w * wv[i + 3];
        }
        long o = (rowbase + r) * 64 + lane;
        Qg[o] = (_Float16)aq; Kg[o] = (_Float16)ak; Vg[o] = (_Float16)av;
    }
}

// ---------------- kernel 2: split-K MFMA flash attention ------------------
// block = (b, w, qt, ci): q-tile 64 rows, chunk = up to 8 k-tiles of 64.
// Partial (O/l, lse) per chunk, merged exactly in mix via LSE identity.
// MFMA 16x16x32 f16. PV computes O^T = Vt(A) * P^T(B) so both operand frags
// are contiguous row-chunk reads. LDS rows are 128B with XOR-chunk swizzle
// (16B-aligned b128, <=2-way banks).
__global__ __launch_bounds__(256, 3) void attn(
        const _Float16* __restrict__ Qg, const _Float16* __restrict__ Kg,
        const _Float16* __restrict__ Vg,
        _Float16* __restrict__ Op, float* __restrict__ LSEp) {
    __shared__ __align__(16) char smem[33280];
    _Float16* Qs = (_Float16*)smem;                 // 8KB (aliased by Osh later)
    _Float16* Ks = (_Float16*)(smem + 8192);
    _Float16* Vt = (_Float16*)(smem + 16384);       // [d][k] transposed V
    _Float16* Ps = (_Float16*)(smem + 24576);
    float* alphaS = (float*)(smem + 32768);         // per-q rescale, this step
    float* lS     = (float*)(smem + 32768 + 256);   // per-q 1/l at end

    // decode (qt, ci) from blockIdx.x in [0,80)
    int id = blockIdx.x;
    int qt, ci;
    if (id < 8)       { qt = id;               ci = 0; }
    else if (id < 24) { int r = id - 8;  qt = 8  + (r >> 1); ci = r & 1; }
    else if (id < 48) { int r = id - 24; int q3 = r / 3; qt = 16 + q3; ci = r - 3 * q3; }
    else              { int r = id - 48; qt = 24 + (r >> 2); ci = r & 3; }
    const int w = blockIdx.y, b = blockIdx.z;
    const int base = win_base(w), stride = win_stride(w);
    const int g = qt >> 3;
    const int outblk = (b * NW + w) * NBLK + (g + 1) * (4 * g + (qt & 7)) + ci;
    const int kt0 = ci * 8;
    const int kt1 = (kt0 + 8 < qt + 1) ? kt0 + 8 : qt + 1;

    const _Float16* Qb = Qg + (size_t)b * NSEQ * 64;
    const _Float16* Kb = Kg + (size_t)b * NSEQ * 64;
    const _Float16* Vb = Vg + (size_t)b * NSEQ * 64;

    const int t = threadIdx.x;
    // stage Q tile (swizzled)
#pragma unroll
    for (int it = 0; it < 2; ++it) {
        int idx = t + it * 256, r = idx >> 3, ch = idx & 7;
        int gr = base + stride * (qt * 64 + r);
        *(half8*)(Qs + r * 64 + ((ch ^ (r & 7)) * 8)) =
            *(const half8*)(Qb + (size_t)gr * 64 + ch * 8);
    }

    const int wv = t >> 6;
    const int lane = t & 63, l15 = lane & 15, quad = lane >> 4;
    const int qrow = 16 * wv + l15;       // A-frag row (QK) / d-row (PV)
    const int swzq = qrow & 7;

    f32x4 oacc[4];
    float m_[4], l_[4];
#pragma unroll
    for (int ns = 0; ns < 4; ++ns) oacc[ns] = (f32x4){0.f, 0.f, 0.f, 0.f};
#pragma unroll
    for (int j = 0; j < 4; ++j) { m_[j] = -1e30f; l_[j] = 0.f; }

    for (int kt = kt0; kt < kt1; ++kt) {
        __syncthreads();   // prev PV reads of Vt/Ps done
        // stage K tile
#pragma unroll
        for (int it = 0; it < 2; ++it) {
            int idx = t + it * 256, r = idx >> 3, ch = idx & 7;
            int gr = base + stride * (kt * 64 + r);
            *(half8*)(Ks + r * 64 + ((ch ^ (r & 7)) * 8)) =
                *(const half8*)(Kb + (size_t)gr * 64 + ch * 8);
        }
        // stage Vt (transpose-pack pairs of k-rows into b32 words)
        {
            int kp = t & 31, d0 = (t >> 5) * 8;
            int gr = base + stride * (kt * 64 + 2 * kp);
            u16x8 r0 = *(const u16x8*)(Vb + (size_t)gr * 64 + d0);
            u16x8 r1 = *(const u16x8*)(Vb + ((size_t)gr + stride) * 64 + d0);
#pragma unroll
            for (int i = 0; i < 8; ++i) {
                int d = d0 + i;
                unsigned int pk = (unsigned int)r0[i] | ((unsigned int)r1[i] << 16);
                *(unsigned int*)((char*)Vt + d * 128 + (((kp >> 2) ^ (d & 7)) * 16)
                                 + (kp & 3) * 4) = pk;
            }
        }
        __syncthreads();

        // ---- QK^T: S[64q x 64k], wave wv owns q-strip [16wv,16wv+16) ----
        half8 a0 = *(half8*)(Qs + qrow * 64 + ((quad ^ swzq) * 8));
        half8 a1 = *(half8*)(Qs + qrow * 64 + (((quad + 4) ^ swzq) * 8));
        f32x4 sa[4];
#pragma unroll
        for (int ns = 0; ns < 4; ++ns) {
            int krow = ns * 16 + l15, swzk = krow & 7;
            half8 b0 = *(half8*)(Ks + krow * 64 + ((quad ^ swzk) * 8));
            half8 b1 = *(half8*)(Ks + krow * 64 + (((quad + 4) ^ swzk) * 8));
            f32x4 c = (f32x4){0.f, 0.f, 0.f, 0.f};
            c = __builtin_amdgcn_mfma_f32_16x16x32_f16(a0, b0, c, 0, 0, 0);
            c = __builtin_amdgcn_mfma_f32_16x16x32_f16(a1, b1, c, 0, 0, 0);
            sa[ns] = c;
        }
#pragma unroll
        for (int ns = 0; ns < 4; ++ns) {
            sa[ns][0] *= 0.125f; sa[ns][1] *= 0.125f;
            sa[ns][2] *= 0.125f; sa[ns][3] *= 0.125f;
        }
        if (kt == qt) {   // causal mask inside diagonal tile
#pragma unroll
            for (int ns = 0; ns < 4; ++ns)
#pragma unroll
                for (int j = 0; j < 4; ++j)
                    if (ns * 16 + l15 > 16 * wv + quad * 4 + j) sa[ns][j] = -1e30f;
        }

        // ---- online softmax (C-layout: lane's reg j = row quad*4+j) ----
        float sc[4];
#pragma unroll
        for (int j = 0; j < 4; ++j) {
            float tm = fmaxf(fmaxf(sa[0][j], sa[1][j]), fmaxf(sa[2][j], sa[3][j]));
#pragma unroll
            for (int d = 1; d < 16; d <<= 1) tm = fmaxf(tm, __shfl_xor(tm, d, 16));
            float mn = fmaxf(m_[j], tm);
            sc[j] = __expf(m_[j] - mn);
            float p[4], rs = 0.f;
#pragma unroll
            for (int ns = 0; ns < 4; ++ns) { p[ns] = __expf(sa[ns][j] - mn); rs += p[ns]; }
#pragma unroll
            for (int d = 1; d < 16; d <<= 1) rs += __shfl_xor(rs, d, 16);
            l_[j] = l_[j] * sc[j] + rs;
            m_[j] = mn;
            int q = 16 * wv + quad * 4 + j, swz = q & 7;
#pragma unroll
            for (int ns = 0; ns < 4; ++ns) {
                int col = ns * 16 + l15;
                Ps[q * 64 + (((col >> 3) ^ swz) * 8) + (col & 7)] = (_Float16)p[ns];
            }
        }
        if (l15 == 0) {
#pragma unroll
            for (int j = 0; j < 4; ++j) alphaS[16 * wv + quad * 4 + j] = sc[j];
        }
        __syncthreads();

        // ---- PV: O^T[d][q] accum. A = Vt rows (d-strip), B = Ps rows ----
        half8 va0 = *(half8*)(Vt + qrow * 64 + ((quad ^ swzq) * 8));
        half8 va1 = *(half8*)(Vt + qrow * 64 + (((quad + 4) ^ swzq) * 8));
#pragma unroll
        for (int ns = 0; ns < 4; ++ns) {
            float al = alphaS[ns * 16 + l15];
            f32x4 o = oacc[ns];
            o[0] *= al; o[1] *= al; o[2] *= al; o[3] *= al;
            int prow = ns * 16 + l15, swzp = prow & 7;
            half8 p0 = *(half8*)(Ps + prow * 64 + ((quad ^ swzp) * 8));
            half8 p1 = *(half8*)(Ps + prow * 64 + (((quad + 4) ^ swzp) * 8));
            o = __builtin_amdgcn_mfma_f32_16x16x32_f16(va0, p0, o, 0, 0, 0);
            o = __builtin_amdgcn_mfma_f32_16x16x32_f16(va1, p1, o, 0, 0, 0);
            oacc[ns] = o;
        }
    }

    // ---- epilogue: 1/l + lse, transpose O^T->O via LDS, store f16 ----
    if (l15 == 0) {
#pragma unroll
        for (int j = 0; j < 4; ++j) {
            int q = 16 * wv + quad * 4 + j;
            lS[q] = 1.0f / l_[j];
            LSEp[(size_t)outblk * 64 + q] = m_[j] + __logf(l_[j]);
        }
    }
    __syncthreads();
    _Float16* Osh = Qs;   // alias: Qs reads all finished before final PV sync
#pragma unroll
    for (int ns = 0; ns < 4; ++ns) {
        float li = lS[ns * 16 + l15];
        int q = ns * 16 + l15, swz = q & 7;
#pragma unroll
        for (int j = 0; j < 4; ++j) {
            int d = 16 * wv + quad * 4 + j;
            Osh[q * 64 + (((d >> 3) ^ swz) * 8) + (d & 7)] = (_Float16)(oacc[ns][j] * li);
        }
    }
    __syncthreads();
#pragma unroll
    for (int it = 0; it < 2; ++it) {
        int idx = t + it * 256, r = idx >> 3, ch = idx & 7;
        *(half8*)(Op + ((size_t)outblk * 64 + r) * 64 + ch * 8) =
            *(half8*)(Osh + r * 64 + ((ch ^ (r & 7)) * 8));
    }
}

// ---------------- kernel 3: merge all (window, chunk) partials ------------
__global__ __launch_bounds__(256) void mix_out(
        const _Float16* __restrict__ Op, const float* __restrict__ LSEp,
        float* __restrict__ out) {
    int gid = blockIdx.x * 256 + threadIdx.x;   // [0, 4*8192*8)
    int f8 = gid & 7;
    int tpos = (gid >> 3) & (NSEQ - 1);
    int b = gid >> 16;

    int idxs[12];
    float lse[12];
    int nref = 0;
    {   // window of stride 1
        int w = tpos >> 11, j = tpos & (M - 1);
        int qt = j >> 6, gg = qt >> 3, q = j & 63;
        int bb = ((b * NW + w) * NBLK + (gg + 1) * (4 * gg + (qt & 7))) * 64 + q;
        for (int c = 0; c <= gg; ++c) { idxs[nref] = bb + c * 64; lse[nref] = LSEp[idxs[nref]]; ++nref; }
    }
    if (!(tpos & 1)) {   // stride 2
        int w = 4 + (tpos >> 12), j = (tpos & 4095) >> 1;
        int qt = j >> 6, gg = qt >> 3, q = j & 63;
        int bb = ((b * NW + w) * NBLK + (gg + 1) * (4 * gg + (qt & 7))) * 64 + q;
        for (int c = 0; c <= gg; ++c) { idxs[nref] = bb + c * 64; lse[nref] = LSEp[idxs[nref]]; ++nref; }
    }
    if (!(tpos & 3)) {   // stride 4
        int j = tpos >> 2;
        int qt = j >> 6, gg = qt >> 3, q = j & 63;
        int bb = ((b * NW + 6) * NBLK + (gg + 1) * (4 * gg + (qt & 7))) * 64 + q;
        for (int c = 0; c <= gg; ++c) { idxs[nref] = bb + c * 64; lse[nref] = LSEp[idxs[nref]]; ++nref; }
    }

    float Mx = -1e30f;
    for (int i = 0; i < nref; ++i) Mx = fmaxf(Mx, lse[i]);
    float acc[8];
#pragma unroll
    for (int k = 0; k < 8; ++k) acc[k] = 0.f;
    float wsum = 0.f;
    for (int i = 0; i < nref; ++i) {
        float a = __expf(lse[i] - Mx);
        wsum += a;
        half8 v = *(const half8*)(Op + (size_t)idxs[i] * 64 + f8 * 8);
#pragma unroll
        for (int k = 0; k < 8; ++k) acc[k] += a * (float)v[k];
    }
    float inv = 1.0f / wsum;
    size_t o = ((size_t)b * NSEQ + tpos) * 64 + f8 * 8;
    float4 r0 = make_float4(acc[0] * inv, acc[1] * inv, acc[2] * inv, acc[3] * inv);
    float4 r1 = make_float4(acc[4] * inv, acc[5] * inv, acc[6] * inv, acc[7] * inv);
    *(float4*)&out[o] = r0;
    *(float4*)&out[o + 4] = r1;
}

extern "C" void kernel_launch(void* const* d_in, const int* in_sizes, int n_in,
                              void* d_out, int out_size, void* d_ws, size_t ws_size,
                              hipStream_t stream) {
    const float* x  = (const float*)d_in[0];
    const float* Wq = (const float*)d_in[1];
    const float* Wk = (const float*)d_in[2];
    const float* Wv = (const float*)d_in[3];
    float* out = (float*)d_out;

    const size_t QN = (size_t)NB * NSEQ * CDIM;     // 2,097,152
    _Float16* Qg = (_Float16*)d_ws;
    _Float16* Kg = Qg + QN;
    _Float16* Vg = Kg + QN;
    _Float16* Op = Vg + QN;                         // [b][w][80][64][64] f16
    float* LSEp  = (float*)(Op + (size_t)NB * NW * NBLK * 64 * 64);

    qkv_proj<<<NB * NSEQ / 32, 64, 0, stream>>>(x, Wq, Wk, Wv, Qg, Kg, Vg);
    attn<<<dim3(NBLK, NW, NB), 256, 0, stream>>>(Qg, Kg, Vg, Op, LSEp);
    mix_out<<<(NB * NSEQ * 8) / 256, 256, 0, stream>>>(Op, LSEp, out);
}